// Round 8
// baseline (203.115 us; speedup 1.0000x reference)
//
#include <hip/hip_runtime.h>
#include <hip/hip_bf16.h>
#include <cfloat>
#include <climits>
#include <cmath>

// Problem constants: B=32, S=2048, H=1024, K=4, PREV=2, R=8
#define BB 32
#define SS 2048
#define HH 1024
#define KK 4
#define CH 32  // s-chunks per batch row in fused_attn (64 rows each)

// ---------------------------------------------------------------------------
// K1: gates partials: part[(kc16*32+b)*6144 + j] = sum_{k in chunk64} A[b,k]*W[j,k]
// grid (24, 16), block 256. One j-row per thread; acc[32] over b.
// ---------------------------------------------------------------------------
__global__ __launch_bounds__(256) void gates_partial(
    const float* __restrict__ x, const float* __restrict__ h_old,
    const float* __restrict__ W_ih, const float* __restrict__ W_hh,
    float* __restrict__ part) {
  int t = threadIdx.x;
  int jb = blockIdx.x;       // 0..23
  int k0 = blockIdx.y * 64;  // k-chunk base
  bool second = (jb >= 12);
  const float* A = second ? h_old : x;
  const float* W = second ? W_hh : W_ih;
  int j0 = jb * 256;                  // global j base
  int jr = j0 - (second ? 3072 : 0);  // row base within W
  const float* wp = W + (size_t)(jr + t) * HH + k0;
  float acc[32];
#pragma unroll
  for (int b = 0; b < 32; b++) acc[b] = 0.f;
  for (int kk = 0; kk < 64; kk += 4) {
    float4 wv = *(const float4*)(wp + kk);
#pragma unroll
    for (int b = 0; b < 32; b++) {
      float4 a = *(const float4*)(A + (size_t)b * HH + k0 + kk);  // uniform
      acc[b] += a.x * wv.x + a.y * wv.y + a.z * wv.z + a.w * wv.w;
    }
  }
  float* pb = part + (size_t)blockIdx.y * (32 * 6144) + j0 + t;
#pragma unroll
  for (int b = 0; b < 32; b++) pb[(size_t)b * 6144] = acc[b];
}

// ---------------------------------------------------------------------------
// K2: gate-reduce + GRU pointwise + q-partial, n-split for parallelism.
// grid (4, 32, 2) = (kc, b, n-half), block 256.
// ---------------------------------------------------------------------------
__global__ __launch_bounds__(256) void gru_q(
    const float* __restrict__ part, const float* __restrict__ b_ih,
    const float* __restrict__ b_hh, const float* __restrict__ h_old,
    const float* __restrict__ Wk, float* __restrict__ h_new,
    float* __restrict__ qpart2) {
  __shared__ float hs[256];
  int t = threadIdx.x;
  int kc = blockIdx.x, b = blockIdx.y, z = blockIdx.z;
  int h = kc * 256 + t;
  float s0 = 0.f, s1 = 0.f, s2 = 0.f, s3 = 0.f, s4 = 0.f, s5 = 0.f;
#pragma unroll
  for (int c = 0; c < 16; c++) {
    const float* p = part + ((size_t)c * 32 + b) * 6144;
    s0 += p[h];
    s1 += p[1024 + h];
    s2 += p[2048 + h];
    s3 += p[3072 + h];
    s4 += p[4096 + h];
    s5 += p[5120 + h];
  }
  float ir = s0 + b_ih[h], iz = s1 + b_ih[1024 + h], in_ = s2 + b_ih[2048 + h];
  float hr = s3 + b_hh[h], hz = s4 + b_hh[1024 + h], hn = s5 + b_hh[2048 + h];
  float r = 1.f / (1.f + expf(-(ir + hr)));
  float z_ = 1.f / (1.f + expf(-(iz + hz)));
  float n = tanhf(in_ + r * hn);
  float hv = (1.f - z_) * n + z_ * h_old[b * HH + h];
  if (z == 0) h_new[b * HH + h] = hv;
  hs[t] = hv;
  __syncthreads();
  // Phase B: q partial over this k-slice, n in [z*512, z*512+512)
  float2 acc = make_float2(0.f, 0.f);
  const float* wb = Wk + (size_t)kc * 256 * HH + z * 512 + 2 * t;
  for (int k = 0; k < 256; k += 4) {
    float2 w0 = *(const float2*)(wb + (size_t)(k + 0) * HH);
    float2 w1 = *(const float2*)(wb + (size_t)(k + 1) * HH);
    float2 w2 = *(const float2*)(wb + (size_t)(k + 2) * HH);
    float2 w3 = *(const float2*)(wb + (size_t)(k + 3) * HH);
    float a0 = hs[k], a1 = hs[k + 1], a2 = hs[k + 2], a3 = hs[k + 3];
    acc.x += a0 * w0.x + a1 * w1.x + a2 * w2.x + a3 * w3.x;
    acc.y += a0 * w0.y + a1 * w1.y + a2 * w2.y + a3 * w3.y;
  }
  *(float2*)(qpart2 + ((size_t)b * 4 + kc) * HH + z * 512 + 2 * t) = acc;
}

// ---------------------------------------------------------------------------
// K3: fused attention (single HBM pass over eo). R7 body, unchanged.
// ---------------------------------------------------------------------------
__global__ __launch_bounds__(256) void fused_attn(
    const float* __restrict__ eo, const float* __restrict__ qpart2,
    const float* __restrict__ h_new, const float* __restrict__ bk,
    const float* __restrict__ mask, float* __restrict__ logits,
    float* __restrict__ c0part, float* __restrict__ msum_part) {
  __shared__ float q_lds[HH];
  __shared__ float wred[4];
  __shared__ float cacc[4][1024];
  __shared__ float cms[4][2];
  int b = blockIdx.y, sc = blockIdx.x, t = threadIdx.x;
  int w = t >> 6, lane = t & 63;
  // ---- preamble: q reduce (4 slices) + hbk block dot ----
  {
    float4 qs = *(const float4*)(qpart2 + ((size_t)b * 4 + 0) * HH + 4 * t);
#pragma unroll
    for (int kc = 1; kc < 4; kc++) {
      float4 v = *(const float4*)(qpart2 + ((size_t)b * 4 + kc) * HH + 4 * t);
      qs.x += v.x; qs.y += v.y; qs.z += v.z; qs.w += v.w;
    }
    *(float4*)&q_lds[4 * t] = qs;
    float4 hv = *(const float4*)(h_new + (size_t)b * HH + 4 * t);
    float4 kv = *(const float4*)(bk + 4 * t);
    float p = hv.x * kv.x + hv.y * kv.y + hv.z * kv.z + hv.w * kv.w;
#pragma unroll
    for (int off = 32; off; off >>= 1) p += __shfl_xor(p, off);
    if (lane == 0) wred[w] = p;
  }
  __syncthreads();
  float hb = wred[0] + wred[1] + wred[2] + wred[3];
  float4 qv[4];
#pragma unroll
  for (int i = 0; i < 4; i++) qv[i] = *(const float4*)&q_lds[(i * 64 + lane) * 4];

  float m = -FLT_MAX, sum = 0.f;
  float4 acc[4];
#pragma unroll
  for (int i = 0; i < 4; i++) acc[i] = make_float4(0.f, 0.f, 0.f, 0.f);
  int rbase = sc * 64 + w * 16;
  // ---- main loop ----
  for (int tile = 0; tile < 8; tile++) {
    int r0 = rbase + tile * 2;
    float4 rv[2][4];
#pragma unroll
    for (int rr = 0; rr < 2; rr++) {
      const float4* e4 = (const float4*)(eo + ((size_t)b * SS + r0 + rr) * HH);
#pragma unroll
      for (int i = 0; i < 4; i++) rv[rr][i] = e4[i * 64 + lane];
    }
    float p0 = 0.f, p1 = 0.f;
#pragma unroll
    for (int i = 0; i < 4; i++) {
      p0 += rv[0][i].x * qv[i].x + rv[0][i].y * qv[i].y +
            rv[0][i].z * qv[i].z + rv[0][i].w * qv[i].w;
      p1 += rv[1][i].x * qv[i].x + rv[1][i].y * qv[i].y +
            rv[1][i].z * qv[i].z + rv[1][i].w * qv[i].w;
    }
#pragma unroll
    for (int off = 32; off; off >>= 1) {
      p0 += __shfl_xor(p0, off);
      p1 += __shfl_xor(p1, off);
    }
    float lv0 = (p0 + hb) * 0.03125f + mask[(size_t)b * SS + r0];
    float lv1 = (p1 + hb) * 0.03125f + mask[(size_t)b * SS + r0 + 1];
    if (lane == 0) {
      logits[(size_t)b * SS + r0] = lv0;
      logits[(size_t)b * SS + r0 + 1] = lv1;
    }
    float m_new = fmaxf(m, fmaxf(lv0, lv1));
    float scale = expf(m - m_new);  // exp(-inf)=0 on first tile
    float w0 = expf(lv0 - m_new), w1 = expf(lv1 - m_new);
    sum = sum * scale + w0 + w1;
#pragma unroll
    for (int i = 0; i < 4; i++) {
      acc[i].x = acc[i].x * scale + w0 * rv[0][i].x + w1 * rv[1][i].x;
      acc[i].y = acc[i].y * scale + w0 * rv[0][i].y + w1 * rv[1][i].y;
      acc[i].z = acc[i].z * scale + w0 * rv[0][i].z + w1 * rv[1][i].z;
      acc[i].w = acc[i].w * scale + w0 * rv[0][i].w + w1 * rv[1][i].w;
    }
    m = m_new;
  }
  // ---- block combine ----
#pragma unroll
  for (int i = 0; i < 4; i++) *(float4*)&cacc[w][i * 256 + lane * 4] = acc[i];
  if (lane == 0) { cms[w][0] = m; cms[w][1] = sum; }
  __syncthreads();
  float m0 = cms[0][0], m1 = cms[1][0], m2 = cms[2][0], m3 = cms[3][0];
  float mb = fmaxf(fmaxf(m0, m1), fmaxf(m2, m3));
  float wt0 = expf(m0 - mb), wt1 = expf(m1 - mb), wt2 = expf(m2 - mb),
        wt3 = expf(m3 - mb);
  float sb = cms[0][1] * wt0 + cms[1][1] * wt1 + cms[2][1] * wt2 + cms[3][1] * wt3;
  float4 a0 = *(float4*)&cacc[0][4 * t];
  float4 a1 = *(float4*)&cacc[1][4 * t];
  float4 a2 = *(float4*)&cacc[2][4 * t];
  float4 a3 = *(float4*)&cacc[3][4 * t];
  float4 r;
  r.x = wt0 * a0.x + wt1 * a1.x + wt2 * a2.x + wt3 * a3.x;
  r.y = wt0 * a0.y + wt1 * a1.y + wt2 * a2.y + wt3 * a3.y;
  r.z = wt0 * a0.z + wt1 * a1.z + wt2 * a2.z + wt3 * a3.z;
  r.w = wt0 * a0.w + wt1 * a1.w + wt2 * a2.w + wt3 * a3.w;
  *(float4*)(c0part + ((size_t)sc * 32 + b) * 1024 + 4 * t) = r;
  if (t == 0) {
    msum_part[((size_t)sc * 32 + b) * 2 + 0] = mb;
    msum_part[((size_t)sc * 32 + b) * 2 + 1] = sb;
  }
}

// ---------------------------------------------------------------------------
// K4: grid 160. Blocks 0..127: c0 combine. Blocks 128..159: top-4 per row.
// ---------------------------------------------------------------------------
__device__ __forceinline__ bool vi_better(float av, int ai, float bv, int bi) {
  return av > bv || (av == bv && ai < bi);
}

__global__ __launch_bounds__(256) void attn_finish(
    const float* __restrict__ c0part, const float* __restrict__ msum_part,
    const float* __restrict__ logits, float* __restrict__ c0,
    float* __restrict__ scores, int* __restrict__ sent) {
  int bid = blockIdx.x, t = threadIdx.x;
  int b = (bid < 128) ? (bid >> 2) : (bid - 128);
  float m = -FLT_MAX;
  float ms[CH];
#pragma unroll
  for (int c = 0; c < CH; c++) {
    ms[c] = msum_part[((size_t)c * 32 + b) * 2 + 0];
    m = fmaxf(m, ms[c]);
  }
  float sum = 0.f;
  float wc[CH];
#pragma unroll
  for (int c = 0; c < CH; c++) {
    wc[c] = expf(ms[c] - m);
    sum += msum_part[((size_t)c * 32 + b) * 2 + 1] * wc[c];
  }
  float inv = 1.f / sum;

  if (bid < 128) {
    int h = (bid & 3) * 256 + t;
    float a = 0.f;
#pragma unroll
    for (int c = 0; c < CH; c++)
      a += wc[c] * c0part[((size_t)c * 32 + b) * 1024 + h];
    c0[(size_t)b * HH + h] = a * inv;
    return;
  }

  float tv0 = -FLT_MAX, tv1 = -FLT_MAX, tv2 = -FLT_MAX, tv3 = -FLT_MAX;
  int ti0 = INT_MAX, ti1 = INT_MAX, ti2 = INT_MAX, ti3 = INT_MAX;
#pragma unroll
  for (int it = 0; it < 8; it++) {
    int idx = it * 256 + t;
    float v = logits[(size_t)b * SS + idx];
    if (vi_better(v, idx, tv3, ti3)) {
      tv3 = v; ti3 = idx;
      if (vi_better(tv3, ti3, tv2, ti2)) { float fv = tv2; int fi = ti2; tv2 = tv3; ti2 = ti3; tv3 = fv; ti3 = fi; }
      if (vi_better(tv2, ti2, tv1, ti1)) { float fv = tv1; int fi = ti1; tv1 = tv2; ti1 = ti2; tv2 = fv; ti2 = fi; }
      if (vi_better(tv1, ti1, tv0, ti0)) { float fv = tv0; int fi = ti0; tv0 = tv1; ti0 = ti1; tv1 = fv; ti1 = fi; }
    }
  }
  __shared__ float sv[256][4];
  __shared__ int si[256][4];
  sv[t][0] = tv0; sv[t][1] = tv1; sv[t][2] = tv2; sv[t][3] = tv3;
  si[t][0] = ti0; si[t][1] = ti1; si[t][2] = ti2; si[t][3] = ti3;
  __syncthreads();
  for (int off = 128; off; off >>= 1) {
    if (t < off) {
      float bv0 = sv[t + off][0], bv1 = sv[t + off][1], bv2 = sv[t + off][2], bv3 = sv[t + off][3];
      int bi0 = si[t + off][0], bi1 = si[t + off][1], bi2 = si[t + off][2], bi3 = si[t + off][3];
      float mv0, mv1, mv2, mv3; int mi0, mi1, mi2, mi3;
      if (vi_better(tv0, ti0, bv3, bi3)) { mv0 = tv0; mi0 = ti0; } else { mv0 = bv3; mi0 = bi3; }
      if (vi_better(tv1, ti1, bv2, bi2)) { mv1 = tv1; mi1 = ti1; } else { mv1 = bv2; mi1 = bi2; }
      if (vi_better(tv2, ti2, bv1, bi1)) { mv2 = tv2; mi2 = ti2; } else { mv2 = bv1; mi2 = bi1; }
      if (vi_better(tv3, ti3, bv0, bi0)) { mv3 = tv3; mi3 = ti3; } else { mv3 = bv0; mi3 = bi0; }
      if (!vi_better(mv0, mi0, mv2, mi2)) { float fv = mv0; int fi = mi0; mv0 = mv2; mi0 = mi2; mv2 = fv; mi2 = fi; }
      if (!vi_better(mv1, mi1, mv3, mi3)) { float fv = mv1; int fi = mi1; mv1 = mv3; mi1 = mi3; mv3 = fv; mi3 = fi; }
      if (!vi_better(mv0, mi0, mv1, mi1)) { float fv = mv0; int fi = mi0; mv0 = mv1; mi0 = mi1; mv1 = fv; mi1 = fi; }
      if (!vi_better(mv2, mi2, mv3, mi3)) { float fv = mv2; int fi = mi2; mv2 = mv3; mi2 = mi3; mv3 = fv; mi3 = fi; }
      tv0 = mv0; tv1 = mv1; tv2 = mv2; tv3 = mv3;
      ti0 = mi0; ti1 = mi1; ti2 = mi2; ti3 = mi3;
      sv[t][0] = tv0; sv[t][1] = tv1; sv[t][2] = tv2; sv[t][3] = tv3;
      si[t][0] = ti0; si[t][1] = ti1; si[t][2] = ti2; si[t][3] = ti3;
    }
    __syncthreads();
  }
  if (t == 0) {
    scores[b * KK + 0] = expf(tv0 - m) * inv; sent[b * KK + 0] = ti0;
    scores[b * KK + 1] = expf(tv1 - m) * inv; sent[b * KK + 1] = ti1;
    scores[b * KK + 2] = expf(tv2 - m) * inv; sent[b * KK + 2] = ti2;
    scores[b * KK + 3] = expf(tv3 - m) * inv; sent[b * KK + 3] = ti3;
  }
}

// ---------------------------------------------------------------------------
// K5: selection + ctx matvec + gather. grid (4, 32), block 256.
// ---------------------------------------------------------------------------
__global__ __launch_bounds__(256) void ctx_sel_gather(
    const float* __restrict__ scores, const int* __restrict__ sent,
    const float* __restrict__ evidence, const int* __restrict__ esi,
    const float* __restrict__ Wv, const float* __restrict__ bvec,
    const float* __restrict__ c0, const float* __restrict__ hnew,
    const float* __restrict__ attn_in, const float* __restrict__ logits,
    const float* __restrict__ mask, float* __restrict__ out0,
    float* __restrict__ out1, float* __restrict__ out2,
    float* __restrict__ out3, float* __restrict__ out4,
    float* __restrict__ out5) {
  __shared__ int s_sh;
  int jq = blockIdx.x, b = blockIdx.y, t = threadIdx.x;
  int w = t >> 6, lane = t & 63;
  if (t == 0) {
    int r = b >> 2, j = b & 3;
    float ls[16];
    bool used[16];
    for (int k1 = 0; k1 < 4; k1++)
      for (int k2 = 0; k2 < 4; k2++)
        ls[k1 * 4 + k2] = -logf(scores[(r * 4 + k1) * 4 + k2]) + evidence[r * 4 + k1];
    for (int i = 0; i < 16; i++) used[i] = false;
    int best = 0;
    float bvv = FLT_MAX;
    for (int jj = 0; jj <= j; jj++) {
      best = 0;
      bvv = FLT_MAX;
      for (int i = 0; i < 16; i++)
        if (!used[i] && ls[i] < bvv) { bvv = ls[i]; best = i; }
      used[best] = true;
    }
    int k1 = best >> 2, k2 = best & 3;
    int sSel = r * 4 + k1;
    s_sh = sSel;
    if (jq == 0) {
      out5[b] = bvv;
      out2[b * 3 + 0] = (float)esi[sSel * 2 + 0];
      out2[b * 3 + 1] = (float)esi[sSel * 2 + 1];
      out2[b * 3 + 2] = (float)sent[sSel * 4 + k2];
    }
  }
  __syncthreads();
  int s = s_sh;
  float4 cv[4];
  const float4* c4 = (const float4*)(c0 + (size_t)s * HH);
#pragma unroll
  for (int i = 0; i < 4; i++) cv[i] = c4[i * 64 + lane];
  int jbase = jq * 256 + w * 64;
  for (int rr = 0; rr < 64; rr++) {
    int j = jbase + rr;
    const float4* w4 = (const float4*)(Wv + (size_t)j * HH);
    float p = 0.f;
#pragma unroll
    for (int i = 0; i < 4; i++) {
      float4 wv = w4[i * 64 + lane];
      p += wv.x * cv[i].x + wv.y * cv[i].y + wv.z * cv[i].z + wv.w * cv[i].w;
    }
#pragma unroll
    for (int off = 32; off; off >>= 1) p += __shfl_xor(p, off);
    if (lane == 0) out0[(size_t)b * HH + j] = p + bvec[j];
  }
  out1[(size_t)b * HH + jq * 256 + t] = hnew[(size_t)s * HH + jq * 256 + t];
#pragma unroll
  for (int p = 0; p < 2; p++) {
    *(float2*)(out3 + ((size_t)p * BB + b) * SS + jq * 512 + 2 * t) =
        *(const float2*)(attn_in + ((size_t)p * BB + s) * SS + jq * 512 + 2 * t);
  }
  *(float2*)(out3 + ((size_t)2 * BB + b) * SS + jq * 512 + 2 * t) =
      *(const float2*)(logits + (size_t)s * SS + jq * 512 + 2 * t);
  *(float2*)(out4 + (size_t)b * SS + jq * 512 + 2 * t) =
      *(const float2*)(mask + (size_t)s * SS + jq * 512 + 2 * t);
}

extern "C" void kernel_launch(void* const* d_in, const int* in_sizes, int n_in,
                              void* d_out, int out_size, void* d_ws, size_t ws_size,
                              hipStream_t stream) {
  const float* h_old = (const float*)d_in[0];
  const float* x     = (const float*)d_in[1];
  const float* eo    = (const float*)d_in[2];
  const float* attn_in = (const float*)d_in[3];
  const float* mask  = (const float*)d_in[4];
  const float* evidence = (const float*)d_in[5];
  const int*   esi   = (const int*)d_in[6];
  const float* W_ih  = (const float*)d_in[7];
  const float* W_hh  = (const float*)d_in[8];
  const float* b_ih  = (const float*)d_in[9];
  const float* b_hh  = (const float*)d_in[10];
  const float* Wk    = (const float*)d_in[11];
  const float* bk    = (const float*)d_in[12];
  const float* Wv    = (const float*)d_in[13];
  const float* bv    = (const float*)d_in[14];

  float* w = (float*)d_ws;
  float* h_new  = w + 0;          // 32768
  float* logits = w + 32768;      // 65536
  float* scores = w + 98304;      // 128
  int*   sent   = (int*)(w + 98432);  // 128
  float* c0     = w + 98560;      // 32768
  float* msum_part = w + 131328;  // 2048
  float* c0part = w + 133376;     // 1,048,576
  float* gpart  = w + 1181952;    // 3,145,728
  float* qpart2 = w + 4327680;    // 131,072
  // A/B measurement scratch (dup fused_attn outputs)
  float* logits2 = w + 4458752;   // 65,536
  float* c0part2 = w + 4524288;   // 1,048,576
  float* msum2   = w + 5572864;   // 2,048

  float* out0 = (float*)d_out;   // result (32,1,1024)
  float* out1 = out0 + 32768;    // hidden (1,32,1024)
  float* out2 = out1 + 32768;    // new_evidence_sentence_index (32,3)
  float* out3 = out2 + 96;       // new_attention_scores (3,32,1,2048)
  float* out4 = out3 + 196608;   // new_attention_mask (32,1,2048)
  float* out5 = out4 + 65536;    // new_evidence_scores (32,)

  gates_partial<<<dim3(24, 16), 256, 0, stream>>>(x, h_old, W_ih, W_hh, gpart);
  gru_q<<<dim3(4, 32, 2), 256, 0, stream>>>(gpart, b_ih, b_hh, h_old, Wk, h_new, qpart2);
  fused_attn<<<dim3(CH, BB), 256, 0, stream>>>(eo, qpart2, h_new, bk, mask,
                                               logits, c0part, msum_part);
  // --- A/B probe: duplicate eo-pass into scratch (deterministic, unread) ---
  fused_attn<<<dim3(CH, BB), 256, 0, stream>>>(eo, qpart2, h_new, bk, mask,
                                               logits2, c0part2, msum2);
  attn_finish<<<160, 256, 0, stream>>>(c0part, msum_part, logits, c0, scores, sent);
  ctx_sel_gather<<<dim3(4, BB), 256, 0, stream>>>(
      scores, sent, evidence, esi, Wv, bv, c0, h_new, attn_in, logits, mask,
      out0, out1, out2, out3, out4, out5);
}

// Round 9
// 177.421 us; speedup vs baseline: 1.1448x; 1.1448x over previous
//
#include <hip/hip_runtime.h>
#include <hip/hip_bf16.h>
#include <cfloat>
#include <climits>
#include <cmath>

// Problem constants: B=32, S=2048, H=1024, K=4, PREV=2, R=8
#define BB 32
#define SS 2048
#define HH 1024
#define KK 4
#define CH 32  // s-chunks per batch row in fused_attn (64 rows each)

// ---------------------------------------------------------------------------
// K1: gates partials, k-chunk 32 for TLP. grid (24, 32), block 256.
// part[(kc*32+b)*6144 + j] = sum_{k in chunk32} A[b,k]*W[j,k]
// ---------------------------------------------------------------------------
__global__ __launch_bounds__(256) void gates_partial(
    const float* __restrict__ x, const float* __restrict__ h_old,
    const float* __restrict__ W_ih, const float* __restrict__ W_hh,
    float* __restrict__ part) {
  int t = threadIdx.x;
  int jb = blockIdx.x;       // 0..23
  int k0 = blockIdx.y * 32;  // k-chunk base
  bool second = (jb >= 12);
  const float* A = second ? h_old : x;
  const float* W = second ? W_hh : W_ih;
  int j0 = jb * 256;
  int jr = j0 - (second ? 3072 : 0);
  const float* wp = W + (size_t)(jr + t) * HH + k0;
  float acc[32];
#pragma unroll
  for (int b = 0; b < 32; b++) acc[b] = 0.f;
#pragma unroll
  for (int kk = 0; kk < 32; kk += 4) {
    float4 wv = *(const float4*)(wp + kk);
#pragma unroll
    for (int b = 0; b < 32; b++) {
      float4 a = *(const float4*)(A + (size_t)b * HH + k0 + kk);  // uniform
      acc[b] += a.x * wv.x + a.y * wv.y + a.z * wv.z + a.w * wv.w;
    }
  }
  float* pb = part + (size_t)blockIdx.y * (32 * 6144) + j0 + t;
#pragma unroll
  for (int b = 0; b < 32; b++) pb[(size_t)b * 6144] = acc[b];
}

// ---------------------------------------------------------------------------
// K2: gate-reduce (32 chunks, 192 independent loads) + GRU pointwise.
// grid (32, 4) = (b, h-tile), block 256.
// ---------------------------------------------------------------------------
__global__ __launch_bounds__(256) void gru_pw(
    const float* __restrict__ part, const float* __restrict__ b_ih,
    const float* __restrict__ b_hh, const float* __restrict__ h_old,
    float* __restrict__ h_new) {
  int t = threadIdx.x;
  int b = blockIdx.x;
  int h = blockIdx.y * 256 + t;
  float s0 = 0.f, s1 = 0.f, s2 = 0.f, s3 = 0.f, s4 = 0.f, s5 = 0.f;
#pragma unroll
  for (int c = 0; c < 32; c++) {
    const float* p = part + ((size_t)c * 32 + b) * 6144;
    s0 += p[h];
    s1 += p[1024 + h];
    s2 += p[2048 + h];
    s3 += p[3072 + h];
    s4 += p[4096 + h];
    s5 += p[5120 + h];
  }
  float ir = s0 + b_ih[h], iz = s1 + b_ih[1024 + h], in_ = s2 + b_ih[2048 + h];
  float hr = s3 + b_hh[h], hz = s4 + b_hh[1024 + h], hn = s5 + b_hh[2048 + h];
  float r = 1.f / (1.f + expf(-(ir + hr)));
  float z = 1.f / (1.f + expf(-(iz + hz)));
  float n = tanhf(in_ + r * hn);
  h_new[b * HH + h] = (1.f - z) * n + z * h_old[b * HH + h];
}

// ---------------------------------------------------------------------------
// K3: qpart[(kc*32+b)*1024 + n] = sum_{k in chunk32} h_new[b,k]*Wk[k,n]
// grid (32, 4) = (kc, n-tile), block 256. Thread owns one n; 4 w-loads +
// uniform h per unrolled iter -> deep load pipeline.
// ---------------------------------------------------------------------------
__global__ __launch_bounds__(256) void q_partial(const float* __restrict__ hnew,
                                                 const float* __restrict__ Wk,
                                                 float* __restrict__ qpart) {
  int t = threadIdx.x;
  int n = blockIdx.y * 256 + t;
  int k0 = blockIdx.x * 32;
  float acc[32];
#pragma unroll
  for (int b = 0; b < 32; b++) acc[b] = 0.f;
#pragma unroll
  for (int k = 0; k < 32; k += 4) {
    float w0 = Wk[(size_t)(k0 + k) * HH + n];
    float w1 = Wk[(size_t)(k0 + k + 1) * HH + n];
    float w2 = Wk[(size_t)(k0 + k + 2) * HH + n];
    float w3 = Wk[(size_t)(k0 + k + 3) * HH + n];
#pragma unroll
    for (int b = 0; b < 32; b++) {
      float4 a = *(const float4*)(hnew + (size_t)b * HH + k0 + k);  // uniform
      acc[b] += a.x * w0 + a.y * w1 + a.z * w2 + a.w * w3;
    }
  }
  float* pb = qpart + (size_t)blockIdx.x * (32 * 1024) + n;
#pragma unroll
  for (int b = 0; b < 32; b++) pb[(size_t)b * 1024] = acc[b];
}

// blocks 0..127: q = sum of 32 chunk partials (32 indep loads).
// block 128: hbk wave-parallel.
__global__ __launch_bounds__(256) void q_reduce_hbk(
    const float* __restrict__ qpart, const float* __restrict__ hnew,
    const float* __restrict__ bk, float* __restrict__ q,
    float* __restrict__ hbk) {
  int t = threadIdx.x;
  if (blockIdx.x < 128) {
    int b = blockIdx.x >> 2;
    int n = (blockIdx.x & 3) * 256 + t;
    float s = 0.f;
#pragma unroll
    for (int kc = 0; kc < 32; kc++) s += qpart[((size_t)kc * 32 + b) * 1024 + n];
    q[b * HH + n] = s;
  } else {
    int w = t >> 6, lane = t & 63;
    const float4* bk4 = (const float4*)bk;
    float4 kv[4];
#pragma unroll
    for (int i = 0; i < 4; i++) kv[i] = bk4[i * 64 + lane];
    for (int b = w; b < BB; b += 4) {
      const float4* h4 = (const float4*)(hnew + (size_t)b * HH);
      float s = 0.f;
#pragma unroll
      for (int i = 0; i < 4; i++) {
        float4 hv = h4[i * 64 + lane];
        s += hv.x * kv[i].x + hv.y * kv[i].y + hv.z * kv[i].z + hv.w * kv[i].w;
      }
#pragma unroll
      for (int off = 32; off; off >>= 1) s += __shfl_xor(s, off);
      if (lane == 0) hbk[b] = s;
    }
  }
}

// ---------------------------------------------------------------------------
// K4: fused attention (single HBM pass over eo). Proven R4 body; direct
// q/hbk reads (no preamble reduce).
// ---------------------------------------------------------------------------
__global__ __launch_bounds__(256) void fused_attn(
    const float* __restrict__ eo, const float* __restrict__ q,
    const float* __restrict__ hbk, const float* __restrict__ mask,
    float* __restrict__ logits, float* __restrict__ c0part,
    float* __restrict__ msum_part) {
  __shared__ float cacc[4][1024];
  __shared__ float cms[4][2];
  int b = blockIdx.y, sc = blockIdx.x, t = threadIdx.x;
  int w = t >> 6, lane = t & 63;
  const float4* q4 = (const float4*)(q + (size_t)b * HH);
  float4 qv[4];
#pragma unroll
  for (int i = 0; i < 4; i++) qv[i] = q4[i * 64 + lane];
  float hb = hbk[b];
  float m = -FLT_MAX, sum = 0.f;
  float4 acc[4];
#pragma unroll
  for (int i = 0; i < 4; i++) acc[i] = make_float4(0.f, 0.f, 0.f, 0.f);
  int rbase = sc * 64 + w * 16;
  for (int tile = 0; tile < 8; tile++) {
    int r0 = rbase + tile * 2;
    float4 rv[2][4];
#pragma unroll
    for (int rr = 0; rr < 2; rr++) {
      const float4* e4 = (const float4*)(eo + ((size_t)b * SS + r0 + rr) * HH);
#pragma unroll
      for (int i = 0; i < 4; i++) rv[rr][i] = e4[i * 64 + lane];
    }
    float p0 = 0.f, p1 = 0.f;
#pragma unroll
    for (int i = 0; i < 4; i++) {
      p0 += rv[0][i].x * qv[i].x + rv[0][i].y * qv[i].y +
            rv[0][i].z * qv[i].z + rv[0][i].w * qv[i].w;
      p1 += rv[1][i].x * qv[i].x + rv[1][i].y * qv[i].y +
            rv[1][i].z * qv[i].z + rv[1][i].w * qv[i].w;
    }
#pragma unroll
    for (int off = 32; off; off >>= 1) {
      p0 += __shfl_xor(p0, off);
      p1 += __shfl_xor(p1, off);
    }
    float lv0 = (p0 + hb) * 0.03125f + mask[(size_t)b * SS + r0];
    float lv1 = (p1 + hb) * 0.03125f + mask[(size_t)b * SS + r0 + 1];
    if (lane == 0) {
      logits[(size_t)b * SS + r0] = lv0;
      logits[(size_t)b * SS + r0 + 1] = lv1;
    }
    float m_new = fmaxf(m, fmaxf(lv0, lv1));
    float scale = expf(m - m_new);  // exp(-inf)=0 on first tile
    float w0 = expf(lv0 - m_new), w1 = expf(lv1 - m_new);
    sum = sum * scale + w0 + w1;
#pragma unroll
    for (int i = 0; i < 4; i++) {
      acc[i].x = acc[i].x * scale + w0 * rv[0][i].x + w1 * rv[1][i].x;
      acc[i].y = acc[i].y * scale + w0 * rv[0][i].y + w1 * rv[1][i].y;
      acc[i].z = acc[i].z * scale + w0 * rv[0][i].z + w1 * rv[1][i].z;
      acc[i].w = acc[i].w * scale + w0 * rv[0][i].w + w1 * rv[1][i].w;
    }
    m = m_new;
  }
#pragma unroll
  for (int i = 0; i < 4; i++) *(float4*)&cacc[w][i * 256 + lane * 4] = acc[i];
  if (lane == 0) { cms[w][0] = m; cms[w][1] = sum; }
  __syncthreads();
  float m0 = cms[0][0], m1 = cms[1][0], m2 = cms[2][0], m3 = cms[3][0];
  float mb = fmaxf(fmaxf(m0, m1), fmaxf(m2, m3));
  float wt0 = expf(m0 - mb), wt1 = expf(m1 - mb), wt2 = expf(m2 - mb),
        wt3 = expf(m3 - mb);
  float sb = cms[0][1] * wt0 + cms[1][1] * wt1 + cms[2][1] * wt2 + cms[3][1] * wt3;
  float4 a0 = *(float4*)&cacc[0][4 * t];
  float4 a1 = *(float4*)&cacc[1][4 * t];
  float4 a2 = *(float4*)&cacc[2][4 * t];
  float4 a3 = *(float4*)&cacc[3][4 * t];
  float4 r;
  r.x = wt0 * a0.x + wt1 * a1.x + wt2 * a2.x + wt3 * a3.x;
  r.y = wt0 * a0.y + wt1 * a1.y + wt2 * a2.y + wt3 * a3.y;
  r.z = wt0 * a0.z + wt1 * a1.z + wt2 * a2.z + wt3 * a3.z;
  r.w = wt0 * a0.w + wt1 * a1.w + wt2 * a2.w + wt3 * a3.w;
  *(float4*)(c0part + ((size_t)sc * 32 + b) * 1024 + 4 * t) = r;
  if (t == 0) {
    msum_part[((size_t)sc * 32 + b) * 2 + 0] = mb;
    msum_part[((size_t)sc * 32 + b) * 2 + 1] = sb;
  }
}

// ---------------------------------------------------------------------------
// K5: grid 160. Blocks 0..127: c0 combine. Blocks 128..159: top-4 per row.
// ---------------------------------------------------------------------------
__device__ __forceinline__ bool vi_better(float av, int ai, float bv, int bi) {
  return av > bv || (av == bv && ai < bi);
}

__global__ __launch_bounds__(256) void attn_finish(
    const float* __restrict__ c0part, const float* __restrict__ msum_part,
    const float* __restrict__ logits, float* __restrict__ c0,
    float* __restrict__ scores, int* __restrict__ sent) {
  int bid = blockIdx.x, t = threadIdx.x;
  int b = (bid < 128) ? (bid >> 2) : (bid - 128);
  float m = -FLT_MAX;
  float ms[CH];
#pragma unroll
  for (int c = 0; c < CH; c++) {
    ms[c] = msum_part[((size_t)c * 32 + b) * 2 + 0];
    m = fmaxf(m, ms[c]);
  }
  float sum = 0.f;
  float wc[CH];
#pragma unroll
  for (int c = 0; c < CH; c++) {
    wc[c] = expf(ms[c] - m);
    sum += msum_part[((size_t)c * 32 + b) * 2 + 1] * wc[c];
  }
  float inv = 1.f / sum;

  if (bid < 128) {
    int h = (bid & 3) * 256 + t;
    float a = 0.f;
#pragma unroll
    for (int c = 0; c < CH; c++)
      a += wc[c] * c0part[((size_t)c * 32 + b) * 1024 + h];
    c0[(size_t)b * HH + h] = a * inv;
    return;
  }

  float tv0 = -FLT_MAX, tv1 = -FLT_MAX, tv2 = -FLT_MAX, tv3 = -FLT_MAX;
  int ti0 = INT_MAX, ti1 = INT_MAX, ti2 = INT_MAX, ti3 = INT_MAX;
#pragma unroll
  for (int it = 0; it < 8; it++) {
    int idx = it * 256 + t;
    float v = logits[(size_t)b * SS + idx];
    if (vi_better(v, idx, tv3, ti3)) {
      tv3 = v; ti3 = idx;
      if (vi_better(tv3, ti3, tv2, ti2)) { float fv = tv2; int fi = ti2; tv2 = tv3; ti2 = ti3; tv3 = fv; ti3 = fi; }
      if (vi_better(tv2, ti2, tv1, ti1)) { float fv = tv1; int fi = ti1; tv1 = tv2; ti1 = ti2; tv2 = fv; ti2 = fi; }
      if (vi_better(tv1, ti1, tv0, ti0)) { float fv = tv0; int fi = ti0; tv0 = tv1; ti0 = ti1; tv1 = fv; ti1 = fi; }
    }
  }
  __shared__ float sv[256][4];
  __shared__ int si[256][4];
  sv[t][0] = tv0; sv[t][1] = tv1; sv[t][2] = tv2; sv[t][3] = tv3;
  si[t][0] = ti0; si[t][1] = ti1; si[t][2] = ti2; si[t][3] = ti3;
  __syncthreads();
  for (int off = 128; off; off >>= 1) {
    if (t < off) {
      float bv0 = sv[t + off][0], bv1 = sv[t + off][1], bv2 = sv[t + off][2], bv3 = sv[t + off][3];
      int bi0 = si[t + off][0], bi1 = si[t + off][1], bi2 = si[t + off][2], bi3 = si[t + off][3];
      float mv0, mv1, mv2, mv3; int mi0, mi1, mi2, mi3;
      if (vi_better(tv0, ti0, bv3, bi3)) { mv0 = tv0; mi0 = ti0; } else { mv0 = bv3; mi0 = bi3; }
      if (vi_better(tv1, ti1, bv2, bi2)) { mv1 = tv1; mi1 = ti1; } else { mv1 = bv2; mi1 = bi2; }
      if (vi_better(tv2, ti2, bv1, bi1)) { mv2 = tv2; mi2 = ti2; } else { mv2 = bv1; mi2 = bi1; }
      if (vi_better(tv3, ti3, bv0, bi0)) { mv3 = tv3; mi3 = ti3; } else { mv3 = bv0; mi3 = bi0; }
      if (!vi_better(mv0, mi0, mv2, mi2)) { float fv = mv0; int fi = mi0; mv0 = mv2; mi0 = mi2; mv2 = fv; mi2 = fi; }
      if (!vi_better(mv1, mi1, mv3, mi3)) { float fv = mv1; int fi = mi1; mv1 = mv3; mi1 = mi3; mv3 = fv; mi3 = fi; }
      if (!vi_better(mv0, mi0, mv1, mi1)) { float fv = mv0; int fi = mi0; mv0 = mv1; mi0 = mi1; mv1 = fv; mi1 = fi; }
      if (!vi_better(mv2, mi2, mv3, mi3)) { float fv = mv2; int fi = mi2; mv2 = mv3; mi2 = mi3; mv3 = fv; mi3 = fi; }
      tv0 = mv0; tv1 = mv1; tv2 = mv2; tv3 = mv3;
      ti0 = mi0; ti1 = mi1; ti2 = mi2; ti3 = mi3;
      sv[t][0] = tv0; sv[t][1] = tv1; sv[t][2] = tv2; sv[t][3] = tv3;
      si[t][0] = ti0; si[t][1] = ti1; si[t][2] = ti2; si[t][3] = ti3;
    }
    __syncthreads();
  }
  if (t == 0) {
    scores[b * KK + 0] = expf(tv0 - m) * inv; sent[b * KK + 0] = ti0;
    scores[b * KK + 1] = expf(tv1 - m) * inv; sent[b * KK + 1] = ti1;
    scores[b * KK + 2] = expf(tv2 - m) * inv; sent[b * KK + 2] = ti2;
    scores[b * KK + 3] = expf(tv3 - m) * inv; sent[b * KK + 3] = ti3;
  }
}

// ---------------------------------------------------------------------------
// K6: selection + ctx matvec (batch-4 rows, 16 loads in flight) + gather.
// grid (8, 32) = (j-eighth, b), block 256.
// ---------------------------------------------------------------------------
__global__ __launch_bounds__(256) void ctx_sel_gather(
    const float* __restrict__ scores, const int* __restrict__ sent,
    const float* __restrict__ evidence, const int* __restrict__ esi,
    const float* __restrict__ Wv, const float* __restrict__ bvec,
    const float* __restrict__ c0, const float* __restrict__ hnew,
    const float* __restrict__ attn_in, const float* __restrict__ logits,
    const float* __restrict__ mask, float* __restrict__ out0,
    float* __restrict__ out1, float* __restrict__ out2,
    float* __restrict__ out3, float* __restrict__ out4,
    float* __restrict__ out5) {
  __shared__ int s_sh;
  int jo = blockIdx.x, b = blockIdx.y, t = threadIdx.x;
  int w = t >> 6, lane = t & 63;
  if (t == 0) {
    int r = b >> 2, j = b & 3;
    float ls[16];
    bool used[16];
    for (int k1 = 0; k1 < 4; k1++)
      for (int k2 = 0; k2 < 4; k2++)
        ls[k1 * 4 + k2] = -logf(scores[(r * 4 + k1) * 4 + k2]) + evidence[r * 4 + k1];
    for (int i = 0; i < 16; i++) used[i] = false;
    int best = 0;
    float bvv = FLT_MAX;
    for (int jj = 0; jj <= j; jj++) {
      best = 0;
      bvv = FLT_MAX;
      for (int i = 0; i < 16; i++)
        if (!used[i] && ls[i] < bvv) { bvv = ls[i]; best = i; }
      used[best] = true;
    }
    int k1 = best >> 2, k2 = best & 3;
    int sSel = r * 4 + k1;
    s_sh = sSel;
    if (jo == 0) {
      out5[b] = bvv;
      out2[b * 3 + 0] = (float)esi[sSel * 2 + 0];
      out2[b * 3 + 1] = (float)esi[sSel * 2 + 1];
      out2[b * 3 + 2] = (float)sent[sSel * 4 + k2];
    }
  }
  __syncthreads();
  int s = s_sh;
  // ---- ctx matvec: wave w handles rows jo*128 + w*32 .. +31, batch 4 ----
  float4 cv[4];
  const float4* c4 = (const float4*)(c0 + (size_t)s * HH);
#pragma unroll
  for (int i = 0; i < 4; i++) cv[i] = c4[i * 64 + lane];
  int jbase = jo * 128 + w * 32;
  for (int rb = 0; rb < 32; rb += 4) {
    float4 wv[4][4];
#pragma unroll
    for (int rr = 0; rr < 4; rr++) {
      const float4* w4 = (const float4*)(Wv + (size_t)(jbase + rb + rr) * HH);
#pragma unroll
      for (int i = 0; i < 4; i++) wv[rr][i] = w4[i * 64 + lane];
    }
    float p[4];
#pragma unroll
    for (int rr = 0; rr < 4; rr++) {
      float s_ = 0.f;
#pragma unroll
      for (int i = 0; i < 4; i++) {
        s_ += wv[rr][i].x * cv[i].x + wv[rr][i].y * cv[i].y +
              wv[rr][i].z * cv[i].z + wv[rr][i].w * cv[i].w;
      }
      p[rr] = s_;
    }
#pragma unroll
    for (int off = 32; off; off >>= 1) {
#pragma unroll
      for (int rr = 0; rr < 4; rr++) p[rr] += __shfl_xor(p[rr], off);
    }
    if (lane == 0) {
#pragma unroll
      for (int rr = 0; rr < 4; rr++) {
        int j = jbase + rb + rr;
        out0[(size_t)b * HH + j] = p[rr] + bvec[j];
      }
    }
  }
  // ---- gathers (eighth slices) ----
  if (t < 128) out1[(size_t)b * HH + jo * 128 + t] = hnew[(size_t)s * HH + jo * 128 + t];
  int col = jo * 256 + t;
#pragma unroll
  for (int p = 0; p < 2; p++)
    out3[((size_t)p * BB + b) * SS + col] = attn_in[((size_t)p * BB + s) * SS + col];
  out3[((size_t)2 * BB + b) * SS + col] = logits[(size_t)s * SS + col];
  out4[(size_t)b * SS + col] = mask[(size_t)s * SS + col];
}

extern "C" void kernel_launch(void* const* d_in, const int* in_sizes, int n_in,
                              void* d_out, int out_size, void* d_ws, size_t ws_size,
                              hipStream_t stream) {
  const float* h_old = (const float*)d_in[0];
  const float* x     = (const float*)d_in[1];
  const float* eo    = (const float*)d_in[2];
  const float* attn_in = (const float*)d_in[3];
  const float* mask  = (const float*)d_in[4];
  const float* evidence = (const float*)d_in[5];
  const int*   esi   = (const int*)d_in[6];
  const float* W_ih  = (const float*)d_in[7];
  const float* W_hh  = (const float*)d_in[8];
  const float* b_ih  = (const float*)d_in[9];
  const float* b_hh  = (const float*)d_in[10];
  const float* Wk    = (const float*)d_in[11];
  const float* bk    = (const float*)d_in[12];
  const float* Wv    = (const float*)d_in[13];
  const float* bv    = (const float*)d_in[14];

  float* w = (float*)d_ws;
  float* h_new  = w + 0;          // 32768
  float* q      = w + 32768;      // 32768
  float* hbk    = w + 65536;      // 32
  float* logits = w + 65568;      // 65536
  float* scores = w + 131104;     // 128
  int*   sent   = (int*)(w + 131232);  // 128
  float* c0     = w + 131360;     // 32768
  float* msum_part = w + 164128;  // 2048
  float* c0part = w + 166176;     // 1,048,576
  float* gpart  = w + 1214752;    // 6,291,456 (32 chunks)
  float* qpart  = w + 7506208;    // 1,048,576 (32 chunks)

  float* out0 = (float*)d_out;   // result (32,1,1024)
  float* out1 = out0 + 32768;    // hidden (1,32,1024)
  float* out2 = out1 + 32768;    // new_evidence_sentence_index (32,3)
  float* out3 = out2 + 96;       // new_attention_scores (3,32,1,2048)
  float* out4 = out3 + 196608;   // new_attention_mask (32,1,2048)
  float* out5 = out4 + 65536;    // new_evidence_scores (32,)

  gates_partial<<<dim3(24, 32), 256, 0, stream>>>(x, h_old, W_ih, W_hh, gpart);
  gru_pw<<<dim3(32, 4), 256, 0, stream>>>(gpart, b_ih, b_hh, h_old, h_new);
  q_partial<<<dim3(32, 4), 256, 0, stream>>>(h_new, Wk, qpart);
  q_reduce_hbk<<<129, 256, 0, stream>>>(qpart, h_new, bk, q, hbk);
  fused_attn<<<dim3(CH, BB), 256, 0, stream>>>(eo, q, hbk, mask, logits,
                                               c0part, msum_part);
  attn_finish<<<160, 256, 0, stream>>>(c0part, msum_part, logits, c0, scores, sent);
  ctx_sel_gather<<<dim3(8, BB), 256, 0, stream>>>(
      scores, sent, evidence, esi, Wv, bv, c0, h_new, attn_in, logits, mask,
      out0, out1, out2, out3, out4, out5);
}

// Round 10
// 135.313 us; speedup vs baseline: 1.5011x; 1.3112x over previous
//
#include <hip/hip_runtime.h>
#include <hip/hip_bf16.h>
#include <cfloat>
#include <climits>
#include <cmath>

// Problem constants: B=32, S=2048, H=1024, K=4, PREV=2, R=8
#define BB 32
#define SS 2048
#define HH 1024
#define KK 4
#define CH 32  // s-chunks per batch row in fused_attn (64 rows each)

// ---------------------------------------------------------------------------
// K1: gates partials: part[(kc16*32+b)*6144 + j] = sum_{k in chunk64} A[b,k]*W[j,k]
// grid (24, 16), block 256. One j-row per thread; acc[32] over b.  [R7 verbatim]
// ---------------------------------------------------------------------------
__global__ __launch_bounds__(256) void gates_partial(
    const float* __restrict__ x, const float* __restrict__ h_old,
    const float* __restrict__ W_ih, const float* __restrict__ W_hh,
    float* __restrict__ part) {
  int t = threadIdx.x;
  int jb = blockIdx.x;       // 0..23
  int k0 = blockIdx.y * 64;  // k-chunk base
  bool second = (jb >= 12);
  const float* A = second ? h_old : x;
  const float* W = second ? W_hh : W_ih;
  int j0 = jb * 256;                  // global j base
  int jr = j0 - (second ? 3072 : 0);  // row base within W
  const float* wp = W + (size_t)(jr + t) * HH + k0;
  float acc[32];
#pragma unroll
  for (int b = 0; b < 32; b++) acc[b] = 0.f;
  for (int kk = 0; kk < 64; kk += 4) {
    float4 wv = *(const float4*)(wp + kk);
#pragma unroll
    for (int b = 0; b < 32; b++) {
      float4 a = *(const float4*)(A + (size_t)b * HH + k0 + kk);  // uniform
      acc[b] += a.x * wv.x + a.y * wv.y + a.z * wv.z + a.w * wv.w;
    }
  }
  float* pb = part + (size_t)blockIdx.y * (32 * 6144) + j0 + t;
#pragma unroll
  for (int b = 0; b < 32; b++) pb[(size_t)b * 6144] = acc[b];
}

// ---------------------------------------------------------------------------
// K2: gate-reduce + GRU pointwise + q-partial, n-split. grid (4,32,2). [R7]
// ---------------------------------------------------------------------------
__global__ __launch_bounds__(256) void gru_q(
    const float* __restrict__ part, const float* __restrict__ b_ih,
    const float* __restrict__ b_hh, const float* __restrict__ h_old,
    const float* __restrict__ Wk, float* __restrict__ h_new,
    float* __restrict__ qpart2) {
  __shared__ float hs[256];
  int t = threadIdx.x;
  int kc = blockIdx.x, b = blockIdx.y, z = blockIdx.z;
  int h = kc * 256 + t;
  float s0 = 0.f, s1 = 0.f, s2 = 0.f, s3 = 0.f, s4 = 0.f, s5 = 0.f;
#pragma unroll
  for (int c = 0; c < 16; c++) {
    const float* p = part + ((size_t)c * 32 + b) * 6144;
    s0 += p[h];
    s1 += p[1024 + h];
    s2 += p[2048 + h];
    s3 += p[3072 + h];
    s4 += p[4096 + h];
    s5 += p[5120 + h];
  }
  float ir = s0 + b_ih[h], iz = s1 + b_ih[1024 + h], in_ = s2 + b_ih[2048 + h];
  float hr = s3 + b_hh[h], hz = s4 + b_hh[1024 + h], hn = s5 + b_hh[2048 + h];
  float r = 1.f / (1.f + expf(-(ir + hr)));
  float z_ = 1.f / (1.f + expf(-(iz + hz)));
  float n = tanhf(in_ + r * hn);
  float hv = (1.f - z_) * n + z_ * h_old[b * HH + h];
  if (z == 0) h_new[b * HH + h] = hv;
  hs[t] = hv;
  __syncthreads();
  // Phase B: q partial over this k-slice, n in [z*512, z*512+512)
  float2 acc = make_float2(0.f, 0.f);
  const float* wb = Wk + (size_t)kc * 256 * HH + z * 512 + 2 * t;
  for (int k = 0; k < 256; k += 4) {
    float2 w0 = *(const float2*)(wb + (size_t)(k + 0) * HH);
    float2 w1 = *(const float2*)(wb + (size_t)(k + 1) * HH);
    float2 w2 = *(const float2*)(wb + (size_t)(k + 2) * HH);
    float2 w3 = *(const float2*)(wb + (size_t)(k + 3) * HH);
    float a0 = hs[k], a1 = hs[k + 1], a2 = hs[k + 2], a3 = hs[k + 3];
    acc.x += a0 * w0.x + a1 * w1.x + a2 * w2.x + a3 * w3.x;
    acc.y += a0 * w0.y + a1 * w1.y + a2 * w2.y + a3 * w3.y;
  }
  *(float2*)(qpart2 + ((size_t)b * 4 + kc) * HH + z * 512 + 2 * t) = acc;
}

// ---------------------------------------------------------------------------
// K3: fused attention (single HBM pass over eo). [R7 verbatim]
// ---------------------------------------------------------------------------
__global__ __launch_bounds__(256) void fused_attn(
    const float* __restrict__ eo, const float* __restrict__ qpart2,
    const float* __restrict__ h_new, const float* __restrict__ bk,
    const float* __restrict__ mask, float* __restrict__ logits,
    float* __restrict__ c0part, float* __restrict__ msum_part) {
  __shared__ float q_lds[HH];
  __shared__ float wred[4];
  __shared__ float cacc[4][1024];
  __shared__ float cms[4][2];
  int b = blockIdx.y, sc = blockIdx.x, t = threadIdx.x;
  int w = t >> 6, lane = t & 63;
  // ---- preamble: q reduce (4 slices) + hbk block dot ----
  {
    float4 qs = *(const float4*)(qpart2 + ((size_t)b * 4 + 0) * HH + 4 * t);
#pragma unroll
    for (int kc = 1; kc < 4; kc++) {
      float4 v = *(const float4*)(qpart2 + ((size_t)b * 4 + kc) * HH + 4 * t);
      qs.x += v.x; qs.y += v.y; qs.z += v.z; qs.w += v.w;
    }
    *(float4*)&q_lds[4 * t] = qs;
    float4 hv = *(const float4*)(h_new + (size_t)b * HH + 4 * t);
    float4 kv = *(const float4*)(bk + 4 * t);
    float p = hv.x * kv.x + hv.y * kv.y + hv.z * kv.z + hv.w * kv.w;
#pragma unroll
    for (int off = 32; off; off >>= 1) p += __shfl_xor(p, off);
    if (lane == 0) wred[w] = p;
  }
  __syncthreads();
  float hb = wred[0] + wred[1] + wred[2] + wred[3];
  float4 qv[4];
#pragma unroll
  for (int i = 0; i < 4; i++) qv[i] = *(const float4*)&q_lds[(i * 64 + lane) * 4];

  float m = -FLT_MAX, sum = 0.f;
  float4 acc[4];
#pragma unroll
  for (int i = 0; i < 4; i++) acc[i] = make_float4(0.f, 0.f, 0.f, 0.f);
  int rbase = sc * 64 + w * 16;
  // ---- main loop ----
  for (int tile = 0; tile < 8; tile++) {
    int r0 = rbase + tile * 2;
    float4 rv[2][4];
#pragma unroll
    for (int rr = 0; rr < 2; rr++) {
      const float4* e4 = (const float4*)(eo + ((size_t)b * SS + r0 + rr) * HH);
#pragma unroll
      for (int i = 0; i < 4; i++) rv[rr][i] = e4[i * 64 + lane];
    }
    float p0 = 0.f, p1 = 0.f;
#pragma unroll
    for (int i = 0; i < 4; i++) {
      p0 += rv[0][i].x * qv[i].x + rv[0][i].y * qv[i].y +
            rv[0][i].z * qv[i].z + rv[0][i].w * qv[i].w;
      p1 += rv[1][i].x * qv[i].x + rv[1][i].y * qv[i].y +
            rv[1][i].z * qv[i].z + rv[1][i].w * qv[i].w;
    }
#pragma unroll
    for (int off = 32; off; off >>= 1) {
      p0 += __shfl_xor(p0, off);
      p1 += __shfl_xor(p1, off);
    }
    float lv0 = (p0 + hb) * 0.03125f + mask[(size_t)b * SS + r0];
    float lv1 = (p1 + hb) * 0.03125f + mask[(size_t)b * SS + r0 + 1];
    if (lane == 0) {
      logits[(size_t)b * SS + r0] = lv0;
      logits[(size_t)b * SS + r0 + 1] = lv1;
    }
    float m_new = fmaxf(m, fmaxf(lv0, lv1));
    float scale = expf(m - m_new);  // exp(-inf)=0 on first tile
    float w0 = expf(lv0 - m_new), w1 = expf(lv1 - m_new);
    sum = sum * scale + w0 + w1;
#pragma unroll
    for (int i = 0; i < 4; i++) {
      acc[i].x = acc[i].x * scale + w0 * rv[0][i].x + w1 * rv[1][i].x;
      acc[i].y = acc[i].y * scale + w0 * rv[0][i].y + w1 * rv[1][i].y;
      acc[i].z = acc[i].z * scale + w0 * rv[0][i].z + w1 * rv[1][i].z;
      acc[i].w = acc[i].w * scale + w0 * rv[0][i].w + w1 * rv[1][i].w;
    }
    m = m_new;
  }
  // ---- block combine ----
#pragma unroll
  for (int i = 0; i < 4; i++) *(float4*)&cacc[w][i * 256 + lane * 4] = acc[i];
  if (lane == 0) { cms[w][0] = m; cms[w][1] = sum; }
  __syncthreads();
  float m0 = cms[0][0], m1 = cms[1][0], m2 = cms[2][0], m3 = cms[3][0];
  float mb = fmaxf(fmaxf(m0, m1), fmaxf(m2, m3));
  float wt0 = expf(m0 - mb), wt1 = expf(m1 - mb), wt2 = expf(m2 - mb),
        wt3 = expf(m3 - mb);
  float sb = cms[0][1] * wt0 + cms[1][1] * wt1 + cms[2][1] * wt2 + cms[3][1] * wt3;
  float4 a0 = *(float4*)&cacc[0][4 * t];
  float4 a1 = *(float4*)&cacc[1][4 * t];
  float4 a2 = *(float4*)&cacc[2][4 * t];
  float4 a3 = *(float4*)&cacc[3][4 * t];
  float4 r;
  r.x = wt0 * a0.x + wt1 * a1.x + wt2 * a2.x + wt3 * a3.x;
  r.y = wt0 * a0.y + wt1 * a1.y + wt2 * a2.y + wt3 * a3.y;
  r.z = wt0 * a0.z + wt1 * a1.z + wt2 * a2.z + wt3 * a3.z;
  r.w = wt0 * a0.w + wt1 * a1.w + wt2 * a2.w + wt3 * a3.w;
  *(float4*)(c0part + ((size_t)sc * 32 + b) * 1024 + 4 * t) = r;
  if (t == 0) {
    msum_part[((size_t)sc * 32 + b) * 2 + 0] = mb;
    msum_part[((size_t)sc * 32 + b) * 2 + 1] = sb;
  }
}

// ---------------------------------------------------------------------------
// K4: grid 160. Blocks 0..127: c0 combine. Blocks 128..159: top-4. [R7]
// ---------------------------------------------------------------------------
__device__ __forceinline__ bool vi_better(float av, int ai, float bv, int bi) {
  return av > bv || (av == bv && ai < bi);
}

__global__ __launch_bounds__(256) void attn_finish(
    const float* __restrict__ c0part, const float* __restrict__ msum_part,
    const float* __restrict__ logits, float* __restrict__ c0,
    float* __restrict__ scores, int* __restrict__ sent) {
  int bid = blockIdx.x, t = threadIdx.x;
  int b = (bid < 128) ? (bid >> 2) : (bid - 128);
  float m = -FLT_MAX;
  float ms[CH];
#pragma unroll
  for (int c = 0; c < CH; c++) {
    ms[c] = msum_part[((size_t)c * 32 + b) * 2 + 0];
    m = fmaxf(m, ms[c]);
  }
  float sum = 0.f;
  float wc[CH];
#pragma unroll
  for (int c = 0; c < CH; c++) {
    wc[c] = expf(ms[c] - m);
    sum += msum_part[((size_t)c * 32 + b) * 2 + 1] * wc[c];
  }
  float inv = 1.f / sum;

  if (bid < 128) {
    int h = (bid & 3) * 256 + t;
    float a = 0.f;
#pragma unroll
    for (int c = 0; c < CH; c++)
      a += wc[c] * c0part[((size_t)c * 32 + b) * 1024 + h];
    c0[(size_t)b * HH + h] = a * inv;
    return;
  }

  float tv0 = -FLT_MAX, tv1 = -FLT_MAX, tv2 = -FLT_MAX, tv3 = -FLT_MAX;
  int ti0 = INT_MAX, ti1 = INT_MAX, ti2 = INT_MAX, ti3 = INT_MAX;
#pragma unroll
  for (int it = 0; it < 8; it++) {
    int idx = it * 256 + t;
    float v = logits[(size_t)b * SS + idx];
    if (vi_better(v, idx, tv3, ti3)) {
      tv3 = v; ti3 = idx;
      if (vi_better(tv3, ti3, tv2, ti2)) { float fv = tv2; int fi = ti2; tv2 = tv3; ti2 = ti3; tv3 = fv; ti3 = fi; }
      if (vi_better(tv2, ti2, tv1, ti1)) { float fv = tv1; int fi = ti1; tv1 = tv2; ti1 = ti2; tv2 = fv; ti2 = fi; }
      if (vi_better(tv1, ti1, tv0, ti0)) { float fv = tv0; int fi = ti0; tv0 = tv1; ti0 = ti1; tv1 = fv; ti1 = fi; }
    }
  }
  __shared__ float sv[256][4];
  __shared__ int si[256][4];
  sv[t][0] = tv0; sv[t][1] = tv1; sv[t][2] = tv2; sv[t][3] = tv3;
  si[t][0] = ti0; si[t][1] = ti1; si[t][2] = ti2; si[t][3] = ti3;
  __syncthreads();
  for (int off = 128; off; off >>= 1) {
    if (t < off) {
      float bv0 = sv[t + off][0], bv1 = sv[t + off][1], bv2 = sv[t + off][2], bv3 = sv[t + off][3];
      int bi0 = si[t + off][0], bi1 = si[t + off][1], bi2 = si[t + off][2], bi3 = si[t + off][3];
      float mv0, mv1, mv2, mv3; int mi0, mi1, mi2, mi3;
      if (vi_better(tv0, ti0, bv3, bi3)) { mv0 = tv0; mi0 = ti0; } else { mv0 = bv3; mi0 = bi3; }
      if (vi_better(tv1, ti1, bv2, bi2)) { mv1 = tv1; mi1 = ti1; } else { mv1 = bv2; mi1 = bi2; }
      if (vi_better(tv2, ti2, bv1, bi1)) { mv2 = tv2; mi2 = ti2; } else { mv2 = bv1; mi2 = bi1; }
      if (vi_better(tv3, ti3, bv0, bi0)) { mv3 = tv3; mi3 = ti3; } else { mv3 = bv0; mi3 = bi0; }
      if (!vi_better(mv0, mi0, mv2, mi2)) { float fv = mv0; int fi = mi0; mv0 = mv2; mi0 = mi2; mv2 = fv; mi2 = fi; }
      if (!vi_better(mv1, mi1, mv3, mi3)) { float fv = mv1; int fi = mi1; mv1 = mv3; mi1 = mi3; mv3 = fv; mi3 = fi; }
      if (!vi_better(mv0, mi0, mv1, mi1)) { float fv = mv0; int fi = mi0; mv0 = mv1; mi0 = mi1; mv1 = fv; mi1 = fi; }
      if (!vi_better(mv2, mi2, mv3, mi3)) { float fv = mv2; int fi = mi2; mv2 = mv3; mi2 = mi3; mv3 = fv; mi3 = fi; }
      tv0 = mv0; tv1 = mv1; tv2 = mv2; tv3 = mv3;
      ti0 = mi0; ti1 = mi1; ti2 = mi2; ti3 = mi3;
      sv[t][0] = tv0; sv[t][1] = tv1; sv[t][2] = tv2; sv[t][3] = tv3;
      si[t][0] = ti0; si[t][1] = ti1; si[t][2] = ti2; si[t][3] = ti3;
    }
    __syncthreads();
  }
  if (t == 0) {
    scores[b * KK + 0] = expf(tv0 - m) * inv; sent[b * KK + 0] = ti0;
    scores[b * KK + 1] = expf(tv1 - m) * inv; sent[b * KK + 1] = ti1;
    scores[b * KK + 2] = expf(tv2 - m) * inv; sent[b * KK + 2] = ti2;
    scores[b * KK + 3] = expf(tv3 - m) * inv; sent[b * KK + 3] = ti3;
  }
}

// ---------------------------------------------------------------------------
// K5: selection + ctx (shuffle-free: thread-per-output-j, c0[s] in LDS,
// streaming Wv row loads with unroll-8 ILP) + gathers. grid (4,32), block 256.
// ---------------------------------------------------------------------------
__global__ __launch_bounds__(256) void ctx_sel_gather(
    const float* __restrict__ scores, const int* __restrict__ sent,
    const float* __restrict__ evidence, const int* __restrict__ esi,
    const float* __restrict__ Wv, const float* __restrict__ bvec,
    const float* __restrict__ c0, const float* __restrict__ hnew,
    const float* __restrict__ attn_in, const float* __restrict__ logits,
    const float* __restrict__ mask, float* __restrict__ out0,
    float* __restrict__ out1, float* __restrict__ out2,
    float* __restrict__ out3, float* __restrict__ out4,
    float* __restrict__ out5) {
  __shared__ int s_sh;
  __shared__ float cs[HH];
  int jq = blockIdx.x, b = blockIdx.y, t = threadIdx.x;
  if (t == 0) {
    int r = b >> 2, j = b & 3;
    float ls[16];
    bool used[16];
    for (int k1 = 0; k1 < 4; k1++)
      for (int k2 = 0; k2 < 4; k2++)
        ls[k1 * 4 + k2] = -logf(scores[(r * 4 + k1) * 4 + k2]) + evidence[r * 4 + k1];
    for (int i = 0; i < 16; i++) used[i] = false;
    int best = 0;
    float bvv = FLT_MAX;
    for (int jj = 0; jj <= j; jj++) {
      best = 0;
      bvv = FLT_MAX;
      for (int i = 0; i < 16; i++)
        if (!used[i] && ls[i] < bvv) { bvv = ls[i]; best = i; }
      used[best] = true;
    }
    int k1 = best >> 2, k2 = best & 3;
    int sSel = r * 4 + k1;
    s_sh = sSel;
    if (jq == 0) {
      out5[b] = bvv;
      out2[b * 3 + 0] = (float)esi[sSel * 2 + 0];
      out2[b * 3 + 1] = (float)esi[sSel * 2 + 1];
      out2[b * 3 + 2] = (float)sent[sSel * 4 + k2];
    }
  }
  __syncthreads();
  int s = s_sh;
  // stage c0[s] into LDS (coalesced)
  *(float4*)&cs[4 * t] = *(const float4*)(c0 + (size_t)s * HH + 4 * t);
  __syncthreads();
  // ---- ctx: thread-per-output-column, no cross-lane ops ----
  {
    int j = jq * 256 + t;
    const float4* w4 = (const float4*)(Wv + (size_t)j * HH);
    float acc = bvec[j];
#pragma unroll 8
    for (int k4 = 0; k4 < 256; k4++) {
      float4 wv = w4[k4];
      float4 cc = *(const float4*)&cs[4 * k4];
      acc += wv.x * cc.x + wv.y * cc.y + wv.z * cc.z + wv.w * cc.w;
    }
    out0[(size_t)b * HH + j] = acc;
  }
  // ---- gathers (quarter slices) ----
  out1[(size_t)b * HH + jq * 256 + t] = hnew[(size_t)s * HH + jq * 256 + t];
#pragma unroll
  for (int p = 0; p < 2; p++) {
    *(float2*)(out3 + ((size_t)p * BB + b) * SS + jq * 512 + 2 * t) =
        *(const float2*)(attn_in + ((size_t)p * BB + s) * SS + jq * 512 + 2 * t);
  }
  *(float2*)(out3 + ((size_t)2 * BB + b) * SS + jq * 512 + 2 * t) =
      *(const float2*)(logits + (size_t)s * SS + jq * 512 + 2 * t);
  *(float2*)(out4 + (size_t)b * SS + jq * 512 + 2 * t) =
      *(const float2*)(mask + (size_t)s * SS + jq * 512 + 2 * t);
}

extern "C" void kernel_launch(void* const* d_in, const int* in_sizes, int n_in,
                              void* d_out, int out_size, void* d_ws, size_t ws_size,
                              hipStream_t stream) {
  const float* h_old = (const float*)d_in[0];
  const float* x     = (const float*)d_in[1];
  const float* eo    = (const float*)d_in[2];
  const float* attn_in = (const float*)d_in[3];
  const float* mask  = (const float*)d_in[4];
  const float* evidence = (const float*)d_in[5];
  const int*   esi   = (const int*)d_in[6];
  const float* W_ih  = (const float*)d_in[7];
  const float* W_hh  = (const float*)d_in[8];
  const float* b_ih  = (const float*)d_in[9];
  const float* b_hh  = (const float*)d_in[10];
  const float* Wk    = (const float*)d_in[11];
  const float* bk    = (const float*)d_in[12];
  const float* Wv    = (const float*)d_in[13];
  const float* bv    = (const float*)d_in[14];

  float* w = (float*)d_ws;
  float* h_new  = w + 0;          // 32768
  float* logits = w + 32768;      // 65536
  float* scores = w + 98304;      // 128
  int*   sent   = (int*)(w + 98432);  // 128
  float* c0     = w + 98560;      // 32768
  float* msum_part = w + 131328;  // 2048
  float* c0part = w + 133376;     // 1,048,576
  float* gpart  = w + 1181952;    // 3,145,728
  float* qpart2 = w + 4327680;    // 131,072

  float* out0 = (float*)d_out;   // result (32,1,1024)
  float* out1 = out0 + 32768;    // hidden (1,32,1024)
  float* out2 = out1 + 32768;    // new_evidence_sentence_index (32,3)
  float* out3 = out2 + 96;       // new_attention_scores (3,32,1,2048)
  float* out4 = out3 + 196608;   // new_attention_mask (32,1,2048)
  float* out5 = out4 + 65536;    // new_evidence_scores (32,)

  gates_partial<<<dim3(24, 16), 256, 0, stream>>>(x, h_old, W_ih, W_hh, gpart);
  gru_q<<<dim3(4, 32, 2), 256, 0, stream>>>(gpart, b_ih, b_hh, h_old, Wk, h_new, qpart2);
  fused_attn<<<dim3(CH, BB), 256, 0, stream>>>(eo, qpart2, h_new, bk, mask,
                                               logits, c0part, msum_part);
  attn_finish<<<160, 256, 0, stream>>>(c0part, msum_part, logits, c0, scores, sent);
  ctx_sel_gather<<<dim3(4, BB), 256, 0, stream>>>(
      scores, sent, evidence, esi, Wv, bv, c0, h_new, attn_in, logits, mask,
      out0, out1, out2, out3, out4, out5);
}